// Round 4
// baseline (224.207 us; speedup 1.0000x reference)
//
#include <hip/hip_runtime.h>

#define Bq 2
#define Lq 2048
#define Dq 1024
#define Hq 16
#define HDq 64

typedef _Float16 f16;
typedef _Float16 f16x8 __attribute__((ext_vector_type(8)));
typedef _Float16 f16x4 __attribute__((ext_vector_type(4)));
typedef __fp16 hf16x2 __attribute__((ext_vector_type(2)));
typedef float f32x4 __attribute__((ext_vector_type(4)));
typedef float f32x16 __attribute__((ext_vector_type(16)));

__device__ __forceinline__ void gload_lds16(const void* g, void* l) {
    __builtin_amdgcn_global_load_lds(
        (const __attribute__((address_space(1))) unsigned int*)g,
        (__attribute__((address_space(3))) unsigned int*)l, 16, 0, 0);
}

// swap upper 32 lanes of a with lower 32 lanes of b (gfx950)
__device__ __forceinline__ void swap32(int& a, int& b) {
    asm volatile("v_permlane32_swap_b32 %0, %1" : "+v"(a), "+v"(b));
}

__device__ __forceinline__ int pk2(float a, float b) {
    hf16x2 v = __builtin_amdgcn_cvt_pkrtz(a, b);
    return __builtin_bit_cast(int, v);
}

// ---------------- fp32 -> fp16 conversion ------------------------------------
__global__ __launch_bounds__(256) void convert_kernel(
    const float* __restrict__ x,
    const float* __restrict__ wq, const float* __restrict__ wk, const float* __restrict__ wv,
    f16* __restrict__ x_h, f16* __restrict__ wq_h, f16* __restrict__ wk_h, f16* __restrict__ wv_h)
{
    const int NX = Bq*Lq*Dq;        // 4194304
    const int NW = Dq*Dq;           // 1048576
    const int total4 = (NX + 3*NW) / 4;
    for (int i = blockIdx.x*blockDim.x + threadIdx.x; i < total4;
         i += gridDim.x*blockDim.x) {
        int e = i * 4;
        const float* src; f16* dst; int off;
        if (e < NX) { src = x; dst = x_h; off = e; }
        else {
            int t = e - NX; int w = t >> 20; off = t & (NW-1);
            src = (w==0) ? wq : (w==1) ? wk : wv;
            dst = (w==0) ? wq_h : (w==1) ? wk_h : wv_h;
        }
        float4 v = *reinterpret_cast<const float4*>(src + off);
        f16x4 hv; hv.x=(f16)v.x; hv.y=(f16)v.y; hv.z=(f16)v.z; hv.w=(f16)v.w;
        *reinterpret_cast<f16x4*>(dst + off) = hv;
    }
}

// ---------------- QKV projection, fp16 MFMA ----------------------------------
#define GBM 128
#define GBN 128
#define GBK 32

__global__ __launch_bounds__(256) void qkv_mfma_kernel(
    const f16* __restrict__ x_h,
    const f16* __restrict__ wq_h, const f16* __restrict__ wk_h, const f16* __restrict__ wv_h,
    f16* __restrict__ q_h, f16* __restrict__ k_h, f16* __restrict__ vT_h)
{
    __shared__ __align__(16) f16 As[GBM*GBK];
    __shared__ __align__(16) f16 Bs[GBN*GBK];

    const int tid  = threadIdx.x;
    const int lane = tid & 63;
    const int wave = tid >> 6;
    const int wr = wave >> 1, wc = wave & 1;
    const int l15 = lane & 15, l4 = lane >> 4;
    const int n0 = blockIdx.x * GBN;
    const int m0 = blockIdx.y * GBM;
    const int z  = blockIdx.z;
    const f16* W = (z==0) ? wq_h : (z==1) ? wk_h : wv_h;

    const int sslot = tid & 3;

    f32x4 acc[4][4];
    #pragma unroll
    for (int i=0;i<4;++i)
        #pragma unroll
        for (int j=0;j<4;++j) acc[i][j] = f32x4{0.f,0.f,0.f,0.f};

    for (int kt = 0; kt < Dq; kt += GBK) {
        __syncthreads();
        #pragma unroll
        for (int j = 0; j < 2; ++j) {
            int slotIdx = tid + j*256;
            int row = slotIdx >> 2;
            gload_lds16(x_h + (size_t)(m0+row)*Dq + kt + sslot*8,
                        (char*)As + slotIdx*16);
            gload_lds16(W   + (size_t)(n0+row)*Dq + kt + sslot*8,
                        (char*)Bs + slotIdx*16);
        }
        __syncthreads();

        f16x8 a[4], b[4];
        #pragma unroll
        for (int m=0;m<4;++m) {
            int row = wr*64 + m*16 + l15;
            a[m] = *reinterpret_cast<const f16x8*>((const char*)As + row*64 + l4*16);
        }
        #pragma unroll
        for (int n=0;n<4;++n) {
            int row = wc*64 + n*16 + l15;
            b[n] = *reinterpret_cast<const f16x8*>((const char*)Bs + row*64 + l4*16);
        }
        #pragma unroll
        for (int m=0;m<4;++m)
            #pragma unroll
            for (int n=0;n<4;++n)
                acc[m][n] = __builtin_amdgcn_mfma_f32_16x16x32_f16(a[m], b[n], acc[m][n], 0,0,0);
    }

    #pragma unroll
    for (int m=0;m<4;++m) {
        #pragma unroll
        for (int r=0;r<4;++r) {
            int grow = m0 + wr*64 + m*16 + l4*4 + r;
            int b_   = grow >> 11;
            int lrow = grow & (Lq-1);
            #pragma unroll
            for (int n=0;n<4;++n) {
                int gcol = n0 + wc*64 + n*16 + l15;
                int h = gcol >> 6, d = gcol & 63;
                int bh = b_*Hq + h;
                f16 val = (f16)acc[m][n][r];
                if (z==0)      q_h[((size_t)bh*Lq + lrow)*HDq + d] = val;
                else if (z==1) k_h[((size_t)bh*Lq + lrow)*HDq + d] = val;
                else           vT_h[((size_t)bh*HDq + d)*Lq + lrow] = val;
            }
        }
    }
}

// ---------------- flash attention, swapped-operand 32x32 MFMA ----------------
// block = 4 waves x 32 q-rows = 128 q-rows of one (b,h). No LDS, no barriers.
__global__ __launch_bounds__(256) void attn32_kernel(
    const f16* __restrict__ q_h, const f16* __restrict__ k_h, const f16* __restrict__ vT_h,
    const float* __restrict__ quantum, const float* __restrict__ scale,
    float* __restrict__ out)
{
    const int tid  = threadIdx.x;
    const int lane = tid & 63;
    const int wave = tid >> 6;
    const int l31  = lane & 31;
    const int hi   = lane >> 5;          // 0/1 half
    const int bh = blockIdx.x;
    const int qb = blockIdx.y;
    const int b_ = bh >> 4, h = bh & 15;
    const int q0 = qb*128 + wave*32;
    const float sc = scale[h];
    const float c1 = 0.125f * sc * 1.44269504f;   // logits -> base-2
    const float c2 = sc * 1.44269504f;

    // Q fragments: B-operand [d][qrow]; lane: qrow=l31, d = ds*16 + hi*8 + e
    f16x8 qf[4];
    {
        const f16* qbase = q_h + ((size_t)bh*Lq + q0 + l31)*HDq + hi*8;
        #pragma unroll
        for (int ds=0; ds<4; ++ds)
            qf[ds] = *reinterpret_cast<const f16x8*>(qbase + ds*16);
    }

    f32x16 oacc0, oacc1;                  // O^T tiles: d 0-31, 32-63
    #pragma unroll
    for (int r=0;r<16;++r) { oacc0[r] = 0.f; oacc1[r] = 0.f; }
    float m_run = -1e30f;                 // running max (base-2), per qrow
    float s_run = 0.f;                    // own-half partial sum

    const f16* kbase = k_h  + (size_t)bh*Lq*HDq;
    const f16* vbase = vT_h + (size_t)bh*HDq*Lq;
    const float* qmbase = quantum + (size_t)b_*Lq*Lq + (size_t)(q0 + l31)*Lq;

    for (int k0 = 0; k0 < Lq; k0 += 64) {
        // ---- issue all loads for this iteration ----
        f16x8 ka0[4], ka1[4], va0[4], va1[4];
        #pragma unroll
        for (int ds=0; ds<4; ++ds) {
            ka0[ds] = *reinterpret_cast<const f16x8*>(
                kbase + (size_t)(k0 + l31)*HDq + ds*16 + hi*8);
            ka1[ds] = *reinterpret_cast<const f16x8*>(
                kbase + (size_t)(k0 + 32 + l31)*HDq + ds*16 + hi*8);
        }
        #pragma unroll
        for (int ks=0; ks<4; ++ks) {
            va0[ks] = *reinterpret_cast<const f16x8*>(
                vbase + (size_t)l31*Lq        + k0 + ks*16 + hi*8);
            va1[ks] = *reinterpret_cast<const f16x8*>(
                vbase + (size_t)(32 + l31)*Lq + k0 + ks*16 + hi*8);
        }
        float qmv[32];
        #pragma unroll
        for (int o=0; o<8; ++o) {
            float4 t = *reinterpret_cast<const float4*>(qmbase + k0 + o*8 + hi*4);
            qmv[o*4+0]=t.x; qmv[o*4+1]=t.y; qmv[o*4+2]=t.z; qmv[o*4+3]=t.w;
        }

        // ---- S^T = K Q^T (two 32-key tiles) ----
        f32x16 st0, st1;
        #pragma unroll
        for (int r=0;r<16;++r) { st0[r]=0.f; st1[r]=0.f; }
        #pragma unroll
        for (int ds=0; ds<4; ++ds) {
            st0 = __builtin_amdgcn_mfma_f32_32x32x16_f16(ka0[ds], qf[ds], st0, 0,0,0);
            st1 = __builtin_amdgcn_mfma_f32_32x32x16_f16(ka1[ds], qf[ds], st1, 0,0,0);
        }

        // ---- logits (base-2); key(idx) matches qmv(idx) layout ----
        float lg[32];
        #pragma unroll
        for (int r=0;r<16;++r) {
            lg[r]    = st0[r]*c1 + qmv[r]*c2;
            lg[16+r] = st1[r]*c1 + qmv[16+r]*c2;
        }

        // ---- tile max (in-lane + cross-half) ----
        float tmax = lg[0];
        #pragma unroll
        for (int r=1;r<32;++r) tmax = fmaxf(tmax, lg[r]);
        tmax = fmaxf(tmax, __shfl_xor(tmax, 32));

        // defer-max (THR = 8 in log2 units -> p <= 256)
        if (!__all(tmax <= m_run + 8.f)) {
            float m_new = fmaxf(m_run, tmax);
            float corr = __builtin_amdgcn_exp2f(m_run - m_new);
            m_run = m_new;
            s_run *= corr;
            #pragma unroll
            for (int r=0;r<16;++r) { oacc0[r] *= corr; oacc1[r] *= corr; }
        }

        // ---- P = 2^(lg - m), own-half sum ----
        float p[32];
        float ts = 0.f;
        #pragma unroll
        for (int r=0;r<32;++r) { p[r] = __builtin_amdgcn_exp2f(lg[r] - m_run); ts += p[r]; }
        s_run += ts;

        // ---- pack P -> B-operand fragments (cvt_pk + permlane32_swap) ----
        f16x8 pb[4];
        #pragma unroll
        for (int ks=0; ks<4; ++ks) {
            int w0 = pk2(p[8*ks+0], p[8*ks+1]);
            int w1 = pk2(p[8*ks+2], p[8*ks+3]);
            int w2 = pk2(p[8*ks+4], p[8*ks+5]);
            int w3 = pk2(p[8*ks+6], p[8*ks+7]);
            swap32(w0, w2);
            swap32(w1, w3);
            union { int w[4]; f16x8 v; } u;
            u.w[0]=w0; u.w[1]=w1; u.w[2]=w2; u.w[3]=w3;
            pb[ks] = u.v;
        }

        // ---- O^T += V^T P^T ----
        #pragma unroll
        for (int ks=0; ks<4; ++ks) {
            oacc0 = __builtin_amdgcn_mfma_f32_32x32x16_f16(va0[ks], pb[ks], oacc0, 0,0,0);
            oacc1 = __builtin_amdgcn_mfma_f32_32x32x16_f16(va1[ks], pb[ks], oacc1, 0,0,0);
        }
    }

    // ---- epilogue ----
    float s_tot = s_run + __shfl_xor(s_run, 32);
    float inv = 1.0f / s_tot;
    float* obase = out + ((size_t)b_*Lq + q0 + l31)*Dq + h*HDq;
    #pragma unroll
    for (int r=0;r<16;++r) {
        int drow = (r&3) + 8*(r>>2) + 4*hi;
        obase[drow]      = oacc0[r]*inv;
        obase[32 + drow] = oacc1[r]*inv;
    }
}

extern "C" void kernel_launch(void* const* d_in, const int* in_sizes, int n_in,
                              void* d_out, int out_size, void* d_ws, size_t ws_size,
                              hipStream_t stream) {
    const float* x       = (const float*)d_in[0];
    const float* quantum = (const float*)d_in[1];
    const float* wq      = (const float*)d_in[2];
    const float* wk      = (const float*)d_in[3];
    const float* wv      = (const float*)d_in[4];
    const float* scale   = (const float*)d_in[5];
    float* out = (float*)d_out;

    f16* ws   = (f16*)d_ws;
    f16* x_h  = ws;
    f16* wq_h = ws + 4194304;
    f16* wk_h = ws + 5242880;
    f16* wv_h = ws + 6291456;
    f16* q_h  = ws + 7340032;
    f16* k_h  = ws + 11534336;
    f16* vT_h = ws + 15728640;

    convert_kernel<<<1024, 256, 0, stream>>>(x, wq, wk, wv, x_h, wq_h, wk_h, wv_h);

    dim3 g1(Dq/GBN, (Bq*Lq)/GBM, 3);
    qkv_mfma_kernel<<<g1, 256, 0, stream>>>(x_h, wq_h, wk_h, wv_h, q_h, k_h, vT_h);

    // grid.x = bh so same-bh blocks land on the same XCD (linear id % 8 = bh % 8)
    dim3 g2(Bq*Hq, Lq/128);
    attn32_kernel<<<g2, 256, 0, stream>>>(q_h, k_h, vT_h, quantum, scale, out);
}

// Round 5
// 145.036 us; speedup vs baseline: 1.5459x; 1.5459x over previous
//
#include <hip/hip_runtime.h>

#define Bq 2
#define Lq 2048
#define Dq 1024
#define Hq 16
#define HDq 64

typedef _Float16 f16;
typedef _Float16 f16x8 __attribute__((ext_vector_type(8)));
typedef _Float16 f16x4 __attribute__((ext_vector_type(4)));
typedef __fp16 hf16x2 __attribute__((ext_vector_type(2)));
typedef float f32x4 __attribute__((ext_vector_type(4)));
typedef float f32x16 __attribute__((ext_vector_type(16)));

__device__ __forceinline__ void gload_lds16(const void* g, void* l) {
    __builtin_amdgcn_global_load_lds(
        (const __attribute__((address_space(1))) unsigned int*)g,
        (__attribute__((address_space(3))) unsigned int*)l, 16, 0, 0);
}

__device__ __forceinline__ void swap32(int& a, int& b) {
    asm volatile("v_permlane32_swap_b32 %0, %1" : "+v"(a), "+v"(b));
}

__device__ __forceinline__ int pk2(float a, float b) {
    hf16x2 v = __builtin_amdgcn_cvt_pkrtz(a, b);
    return __builtin_bit_cast(int, v);
}

// ---------------- fp32 -> fp16 conversion ------------------------------------
__global__ __launch_bounds__(256) void convert_kernel(
    const float* __restrict__ x,
    const float* __restrict__ wq, const float* __restrict__ wk, const float* __restrict__ wv,
    f16* __restrict__ x_h, f16* __restrict__ wq_h, f16* __restrict__ wk_h, f16* __restrict__ wv_h)
{
    const int NX = Bq*Lq*Dq;
    const int NW = Dq*Dq;
    const int total4 = (NX + 3*NW) / 4;
    for (int i = blockIdx.x*blockDim.x + threadIdx.x; i < total4;
         i += gridDim.x*blockDim.x) {
        int e = i * 4;
        const float* src; f16* dst; int off;
        if (e < NX) { src = x; dst = x_h; off = e; }
        else {
            int t = e - NX; int w = t >> 20; off = t & (NW-1);
            src = (w==0) ? wq : (w==1) ? wk : wv;
            dst = (w==0) ? wq_h : (w==1) ? wk_h : wv_h;
        }
        float4 v = *reinterpret_cast<const float4*>(src + off);
        f16x4 hv; hv.x=(f16)v.x; hv.y=(f16)v.y; hv.z=(f16)v.z; hv.w=(f16)v.w;
        *reinterpret_cast<f16x4*>(dst + off) = hv;
    }
}

// ---------------- QKV projection, fp16 MFMA ----------------------------------
#define GBM 128
#define GBN 128
#define GBK 32

__global__ __launch_bounds__(256) void qkv_mfma_kernel(
    const f16* __restrict__ x_h,
    const f16* __restrict__ wq_h, const f16* __restrict__ wk_h, const f16* __restrict__ wv_h,
    f16* __restrict__ q_h, f16* __restrict__ k_h, f16* __restrict__ vT_h)
{
    __shared__ __align__(16) f16 As[GBM*GBK];
    __shared__ __align__(16) f16 Bs[GBN*GBK];

    const int tid  = threadIdx.x;
    const int lane = tid & 63;
    const int wave = tid >> 6;
    const int wr = wave >> 1, wc = wave & 1;
    const int l15 = lane & 15, l4 = lane >> 4;
    const int n0 = blockIdx.x * GBN;
    const int m0 = blockIdx.y * GBM;
    const int z  = blockIdx.z;
    const f16* W = (z==0) ? wq_h : (z==1) ? wk_h : wv_h;

    const int sslot = tid & 3;

    f32x4 acc[4][4];
    #pragma unroll
    for (int i=0;i<4;++i)
        #pragma unroll
        for (int j=0;j<4;++j) acc[i][j] = f32x4{0.f,0.f,0.f,0.f};

    for (int kt = 0; kt < Dq; kt += GBK) {
        __syncthreads();
        #pragma unroll
        for (int j = 0; j < 2; ++j) {
            int slotIdx = tid + j*256;
            int row = slotIdx >> 2;
            gload_lds16(x_h + (size_t)(m0+row)*Dq + kt + sslot*8,
                        (char*)As + slotIdx*16);
            gload_lds16(W   + (size_t)(n0+row)*Dq + kt + sslot*8,
                        (char*)Bs + slotIdx*16);
        }
        __syncthreads();

        f16x8 a[4], b[4];
        #pragma unroll
        for (int m=0;m<4;++m) {
            int row = wr*64 + m*16 + l15;
            a[m] = *reinterpret_cast<const f16x8*>((const char*)As + row*64 + l4*16);
        }
        #pragma unroll
        for (int n=0;n<4;++n) {
            int row = wc*64 + n*16 + l15;
            b[n] = *reinterpret_cast<const f16x8*>((const char*)Bs + row*64 + l4*16);
        }
        #pragma unroll
        for (int m=0;m<4;++m)
            #pragma unroll
            for (int n=0;n<4;++n)
                acc[m][n] = __builtin_amdgcn_mfma_f32_16x16x32_f16(a[m], b[n], acc[m][n], 0,0,0);
    }

    #pragma unroll
    for (int m=0;m<4;++m) {
        #pragma unroll
        for (int r=0;r<4;++r) {
            int grow = m0 + wr*64 + m*16 + l4*4 + r;
            int b_   = grow >> 11;
            int lrow = grow & (Lq-1);
            #pragma unroll
            for (int n=0;n<4;++n) {
                int gcol = n0 + wc*64 + n*16 + l15;
                int h = gcol >> 6, d = gcol & 63;
                int bh = b_*Hq + h;
                f16 val = (f16)acc[m][n][r];
                if (z==0)      q_h[((size_t)bh*Lq + lrow)*HDq + d] = val;
                else if (z==1) k_h[((size_t)bh*Lq + lrow)*HDq + d] = val;
                else           vT_h[((size_t)bh*HDq + d)*Lq + lrow] = val;
            }
        }
    }
}

// ---------------- quantum -> fragment-ordered fp16 tiles ---------------------
// qm_pre tile (b, kt64, qt32): 4KB, addr = seg*1024B + lane*16B, f16[8] where
// element e of (seg,lane) = quantum[b][qt*32+(lane&31)][kt*64 + 16*seg + 8*(e>>2) + 4*(lane>>5) + (e&3)]
__global__ __launch_bounds__(256) void qm_pre_kernel(
    const float* __restrict__ quantum, f16* __restrict__ qm_pre)
{
    __shared__ float qs[32][64];
    const int tid = threadIdx.x;
    const int qt = blockIdx.x, kt = blockIdx.y, b = blockIdx.z;
    const float* base = quantum + ((size_t)b*Lq + qt*32)*Lq + kt*64;
    #pragma unroll
    for (int i=0;i<2;++i) {
        int idx = tid + i*256;
        int r = idx >> 4, c = (idx & 15)*4;
        float4 v = *reinterpret_cast<const float4*>(base + (size_t)r*Lq + c);
        qs[r][c]=v.x; qs[r][c+1]=v.y; qs[r][c+2]=v.z; qs[r][c+3]=v.w;
    }
    __syncthreads();
    const int seg = tid >> 6, lane = tid & 63, l31 = lane & 31, hi = lane >> 5;
    f16x8 u;
    #pragma unroll
    for (int e=0;e<8;++e) {
        int key = 16*seg + 8*(e>>2) + 4*hi + (e&3);
        u[e] = (f16)qs[l31][key];
    }
    f16* outp = qm_pre + (((size_t)b*32 + kt)*64 + qt)*2048 + seg*512 + lane*8;
    *reinterpret_cast<f16x8*>(outp) = u;
}

// ---------------- flash attention: 4 waves x 64 q-rows, LDS-staged K/V -------
__global__ __launch_bounds__(256, 1) void attn64_kernel(
    const f16* __restrict__ q_h, const f16* __restrict__ k_h, const f16* __restrict__ vT_h,
    const f16* __restrict__ qm_pre, const float* __restrict__ scale,
    float* __restrict__ out)
{
    __shared__ __align__(16) char lds[32768];   // [buf][K 8KB | V 8KB] x2

    const int tid  = threadIdx.x;
    const int lane = tid & 63;
    const int wave = tid >> 6;
    const int l31  = lane & 31;
    const int hi   = lane >> 5;
    const int bh = blockIdx.x;
    const int qb = blockIdx.y;
    const int b_ = bh >> 4, h = bh & 15;
    const int qW = qb*256 + wave*64;           // this wave's q base (64 rows)
    const int qtA = (qW) >> 5;                 // 32-row quantum tile indices
    const float sc = scale[h];
    const float c1 = 0.125f * sc * 1.44269504f;
    const float c2 = sc * 1.44269504f;

    const f16* kbase = k_h  + (size_t)bh*Lq*HDq;
    const f16* vbase = vT_h + (size_t)bh*HDq*Lq;

    // Q fragments for both q-halves (B-operand: qrow=l31, d = ds*16+hi*8+e)
    f16x8 qfA[4], qfB[4];
    {
        const f16* qbA = q_h + ((size_t)bh*Lq + qW + l31)*HDq + hi*8;
        const f16* qbB = qbA + 32*HDq;
        #pragma unroll
        for (int ds=0; ds<4; ++ds) {
            qfA[ds] = *reinterpret_cast<const f16x8*>(qbA + ds*16);
            qfB[ds] = *reinterpret_cast<const f16x8*>(qbB + ds*16);
        }
    }

    f32x16 oA0, oA1, oB0, oB1;
    #pragma unroll
    for (int r=0;r<16;++r) { oA0[r]=0.f; oA1[r]=0.f; oB0[r]=0.f; oB1[r]=0.f; }
    float mA = -1e30f, sA = 0.f, mB = -1e30f, sB = 0.f;

    auto STAGE = [&](int t, int buf) {
        const int k0 = t*64;
        char* LK = lds + buf*16384;
        char* LV = LK + 8192;
        #pragma unroll
        for (int i=0;i<2;++i) {
            int g = tid + i*256;                 // 0..511
            int row = g >> 3, slot = g & 7;
            int ss = slot ^ (row & 7);
            gload_lds16(kbase + (size_t)(k0+row)*HDq + ss*8, LK + g*16);
            gload_lds16(vbase + (size_t)row*Lq + k0 + ss*8,  LV + g*16);
        }
    };

    auto HALF = [&](f32x16 st[2], f16x8 qm[4], float& m_run, float& s_run,
                    f32x16& o0, f32x16& o1, f16x8 pb[4]) {
        float lg[32];
        #pragma unroll
        for (int s=0;s<4;++s)
            #pragma unroll
            for (int e=0;e<8;++e) {
                int i = s*8 + e;
                float sv = (i < 16) ? st[0][i] : st[1][i-16];
                lg[i] = sv*c1 + (float)qm[s][e]*c2;
            }
        float tmax = lg[0];
        #pragma unroll
        for (int r=1;r<32;++r) tmax = fmaxf(tmax, lg[r]);
        tmax = fmaxf(tmax, __shfl_xor(tmax, 32));
        if (!__all(tmax <= m_run + 8.f)) {
            float m_new = fmaxf(m_run, tmax);
            float corr = __builtin_amdgcn_exp2f(m_run - m_new);
            m_run = m_new;
            s_run *= corr;
            #pragma unroll
            for (int r=0;r<16;++r) { o0[r] *= corr; o1[r] *= corr; }
        }
        float p[32], ts = 0.f;
        #pragma unroll
        for (int r=0;r<32;++r) { p[r] = __builtin_amdgcn_exp2f(lg[r] - m_run); ts += p[r]; }
        s_run += ts;
        #pragma unroll
        for (int ks=0; ks<4; ++ks) {
            int w0 = pk2(p[8*ks+0], p[8*ks+1]);
            int w1 = pk2(p[8*ks+2], p[8*ks+3]);
            int w2 = pk2(p[8*ks+4], p[8*ks+5]);
            int w3 = pk2(p[8*ks+6], p[8*ks+7]);
            swap32(w0, w2);
            swap32(w1, w3);
            union { int w[4]; f16x8 v; } u;
            u.w[0]=w0; u.w[1]=w1; u.w[2]=w2; u.w[3]=w3;
            pb[ks] = u.v;
        }
    };

    auto COMPUTE = [&](int t, int buf) {
        const char* LK = lds + buf*16384;
        const char* LV = LK + 8192;
        // quantum fragments (coalesced, element order == register order)
        f16x8 qmA[4], qmB[4];
        const f16* qmbA = qm_pre + (((size_t)b_*32 + t)*64 + qtA)*2048 + lane*8;
        #pragma unroll
        for (int s=0;s<4;++s) {
            qmA[s] = *reinterpret_cast<const f16x8*>(qmbA + s*512);
            qmB[s] = *reinterpret_cast<const f16x8*>(qmbA + 2048 + s*512);
        }
        // S^T = K Q^T for both q-halves (shared K fragments)
        f32x16 stA[2], stB[2];
        #pragma unroll
        for (int kt=0;kt<2;++kt) {
            #pragma unroll
            for (int r=0;r<16;++r) { stA[kt][r]=0.f; stB[kt][r]=0.f; }
            #pragma unroll
            for (int ds=0;ds<4;++ds) {
                f16x8 ka = *reinterpret_cast<const f16x8*>(
                    LK + ((kt*32+l31)<<7) + (((ds*2+hi)^(l31&7))<<4));
                stA[kt] = __builtin_amdgcn_mfma_f32_32x32x16_f16(ka, qfA[ds], stA[kt], 0,0,0);
                stB[kt] = __builtin_amdgcn_mfma_f32_32x32x16_f16(ka, qfB[ds], stB[kt], 0,0,0);
            }
        }
        f16x8 pbA[4], pbB[4];
        HALF(stA, qmA, mA, sA, oA0, oA1, pbA);
        HALF(stB, qmB, mB, sB, oB0, oB1, pbB);
        // O^T += V^T P^T (shared V fragments)
        #pragma unroll
        for (int ks=0; ks<4; ++ks) {
            #pragma unroll
            for (int vt=0; vt<2; ++vt) {
                f16x8 va = *reinterpret_cast<const f16x8*>(
                    LV + ((vt*32+l31)<<7) + (((ks*2+hi)^(l31&7))<<4));
                if (vt==0) {
                    oA0 = __builtin_amdgcn_mfma_f32_32x32x16_f16(va, pbA[ks], oA0, 0,0,0);
                    oB0 = __builtin_amdgcn_mfma_f32_32x32x16_f16(va, pbB[ks], oB0, 0,0,0);
                } else {
                    oA1 = __builtin_amdgcn_mfma_f32_32x32x16_f16(va, pbA[ks], oA1, 0,0,0);
                    oB1 = __builtin_amdgcn_mfma_f32_32x32x16_f16(va, pbB[ks], oB1, 0,0,0);
                }
            }
        }
    };

    STAGE(0, 0);
    STAGE(1, 1);
    for (int t = 0; t < 31; ++t) {
        asm volatile("s_waitcnt vmcnt(4)" ::: "memory");
        __builtin_amdgcn_s_barrier();
        COMPUTE(t, t & 1);
        asm volatile("s_waitcnt lgkmcnt(0)" ::: "memory");
        __builtin_amdgcn_sched_barrier(0);
        __builtin_amdgcn_s_barrier();
        if (t < 30) STAGE(t+2, t & 1);
    }
    asm volatile("s_waitcnt vmcnt(0)" ::: "memory");
    __builtin_amdgcn_s_barrier();
    COMPUTE(31, 1);

    // epilogue
    float sAt = sA + __shfl_xor(sA, 32);
    float sBt = sB + __shfl_xor(sB, 32);
    float invA = 1.0f / sAt, invB = 1.0f / sBt;
    float* obA = out + ((size_t)b_*Lq + qW + l31)*Dq + h*HDq;
    float* obB = obA + (size_t)32*Dq;
    #pragma unroll
    for (int r=0;r<16;++r) {
        int drow = (r&3) + 8*(r>>2) + 4*hi;
        obA[drow]      = oA0[r]*invA;
        obA[32 + drow] = oA1[r]*invA;
        obB[drow]      = oB0[r]*invB;
        obB[32 + drow] = oB1[r]*invB;
    }
}

extern "C" void kernel_launch(void* const* d_in, const int* in_sizes, int n_in,
                              void* d_out, int out_size, void* d_ws, size_t ws_size,
                              hipStream_t stream) {
    const float* x       = (const float*)d_in[0];
    const float* quantum = (const float*)d_in[1];
    const float* wq      = (const float*)d_in[2];
    const float* wk      = (const float*)d_in[3];
    const float* wv      = (const float*)d_in[4];
    const float* scale   = (const float*)d_in[5];
    float* out = (float*)d_out;

    f16* ws     = (f16*)d_ws;
    f16* x_h    = ws;                    // 4,194,304
    f16* wq_h   = ws + 4194304;
    f16* wk_h   = ws + 5242880;
    f16* wv_h   = ws + 6291456;
    f16* q_h    = ws + 7340032;
    f16* k_h    = ws + 11534336;
    f16* vT_h   = ws + 15728640;
    f16* qm_pre = ws + 19922944;         // 8,388,608 f16 -> total 56.6 MB

    convert_kernel<<<1024, 256, 0, stream>>>(x, wq, wk, wv, x_h, wq_h, wk_h, wv_h);

    dim3 gq(64, 32, 2);
    qm_pre_kernel<<<gq, 256, 0, stream>>>(quantum, qm_pre);

    dim3 g1(Dq/GBN, (Bq*Lq)/GBM, 3);
    qkv_mfma_kernel<<<g1, 256, 0, stream>>>(x_h, wq_h, wk_h, wv_h, q_h, k_h, vT_h);

    dim3 g2(Bq*Hq, Lq/256);
    attn64_kernel<<<g2, 256, 0, stream>>>(q_h, k_h, vT_h, qm_pre, scale, out);
}

// Round 6
// 137.717 us; speedup vs baseline: 1.6280x; 1.0531x over previous
//
#include <hip/hip_runtime.h>

#define Bq 2
#define Lq 2048
#define Dq 1024
#define Hq 16
#define HDq 64

typedef _Float16 f16;
typedef _Float16 f16x8 __attribute__((ext_vector_type(8)));
typedef _Float16 f16x4 __attribute__((ext_vector_type(4)));
typedef __fp16 hf16x2 __attribute__((ext_vector_type(2)));
typedef float f32x4 __attribute__((ext_vector_type(4)));
typedef float f32x16 __attribute__((ext_vector_type(16)));

__device__ __forceinline__ void gload_lds16(const void* g, void* l) {
    __builtin_amdgcn_global_load_lds(
        (const __attribute__((address_space(1))) unsigned int*)g,
        (__attribute__((address_space(3))) unsigned int*)l, 16, 0, 0);
}

__device__ __forceinline__ void swap32(int& a, int& b) {
    asm volatile("v_permlane32_swap_b32 %0, %1" : "+v"(a), "+v"(b));
}

__device__ __forceinline__ int pk2(float a, float b) {
    hf16x2 v = __builtin_amdgcn_cvt_pkrtz(a, b);
    return __builtin_bit_cast(int, v);
}

// ---------------- fp32 -> fp16 conversion ------------------------------------
__global__ __launch_bounds__(256) void convert_kernel(
    const float* __restrict__ x,
    const float* __restrict__ wq, const float* __restrict__ wk, const float* __restrict__ wv,
    f16* __restrict__ x_h, f16* __restrict__ wq_h, f16* __restrict__ wk_h, f16* __restrict__ wv_h)
{
    const int NX = Bq*Lq*Dq;
    const int NW = Dq*Dq;
    const int total4 = (NX + 3*NW) / 4;
    for (int i = blockIdx.x*blockDim.x + threadIdx.x; i < total4;
         i += gridDim.x*blockDim.x) {
        int e = i * 4;
        const float* src; f16* dst; int off;
        if (e < NX) { src = x; dst = x_h; off = e; }
        else {
            int t = e - NX; int w = t >> 20; off = t & (NW-1);
            src = (w==0) ? wq : (w==1) ? wk : wv;
            dst = (w==0) ? wq_h : (w==1) ? wk_h : wv_h;
        }
        float4 v = *reinterpret_cast<const float4*>(src + off);
        f16x4 hv; hv.x=(f16)v.x; hv.y=(f16)v.y; hv.z=(f16)v.z; hv.w=(f16)v.w;
        *reinterpret_cast<f16x4*>(dst + off) = hv;
    }
}

// ---------------- QKV projection, fp16 MFMA ----------------------------------
#define GBM 128
#define GBN 128
#define GBK 32

__global__ __launch_bounds__(256) void qkv_mfma_kernel(
    const f16* __restrict__ x_h,
    const f16* __restrict__ wq_h, const f16* __restrict__ wk_h, const f16* __restrict__ wv_h,
    f16* __restrict__ q_h, f16* __restrict__ k_h, f16* __restrict__ vT_h)
{
    __shared__ __align__(16) f16 As[GBM*GBK];
    __shared__ __align__(16) f16 Bs[GBN*GBK];

    const int tid  = threadIdx.x;
    const int lane = tid & 63;
    const int wave = tid >> 6;
    const int wr = wave >> 1, wc = wave & 1;
    const int l15 = lane & 15, l4 = lane >> 4;
    const int n0 = blockIdx.x * GBN;
    const int m0 = blockIdx.y * GBM;
    const int z  = blockIdx.z;
    const f16* W = (z==0) ? wq_h : (z==1) ? wk_h : wv_h;

    const int sslot = tid & 3;

    f32x4 acc[4][4];
    #pragma unroll
    for (int i=0;i<4;++i)
        #pragma unroll
        for (int j=0;j<4;++j) acc[i][j] = f32x4{0.f,0.f,0.f,0.f};

    for (int kt = 0; kt < Dq; kt += GBK) {
        __syncthreads();
        #pragma unroll
        for (int j = 0; j < 2; ++j) {
            int slotIdx = tid + j*256;
            int row = slotIdx >> 2;
            gload_lds16(x_h + (size_t)(m0+row)*Dq + kt + sslot*8,
                        (char*)As + slotIdx*16);
            gload_lds16(W   + (size_t)(n0+row)*Dq + kt + sslot*8,
                        (char*)Bs + slotIdx*16);
        }
        __syncthreads();

        f16x8 a[4], b[4];
        #pragma unroll
        for (int m=0;m<4;++m) {
            int row = wr*64 + m*16 + l15;
            a[m] = *reinterpret_cast<const f16x8*>((const char*)As + row*64 + l4*16);
        }
        #pragma unroll
        for (int n=0;n<4;++n) {
            int row = wc*64 + n*16 + l15;
            b[n] = *reinterpret_cast<const f16x8*>((const char*)Bs + row*64 + l4*16);
        }
        #pragma unroll
        for (int m=0;m<4;++m)
            #pragma unroll
            for (int n=0;n<4;++n)
                acc[m][n] = __builtin_amdgcn_mfma_f32_16x16x32_f16(a[m], b[n], acc[m][n], 0,0,0);
    }

    #pragma unroll
    for (int m=0;m<4;++m) {
        #pragma unroll
        for (int r=0;r<4;++r) {
            int grow = m0 + wr*64 + m*16 + l4*4 + r;
            int b_   = grow >> 11;
            int lrow = grow & (Lq-1);
            #pragma unroll
            for (int n=0;n<4;++n) {
                int gcol = n0 + wc*64 + n*16 + l15;
                int h = gcol >> 6, d = gcol & 63;
                int bh = b_*Hq + h;
                f16 val = (f16)acc[m][n][r];
                if (z==0)      q_h[((size_t)bh*Lq + lrow)*HDq + d] = val;
                else if (z==1) k_h[((size_t)bh*Lq + lrow)*HDq + d] = val;
                else           vT_h[((size_t)bh*HDq + d)*Lq + lrow] = val;
            }
        }
    }
}

// ---------------- quantum -> fragment-ordered fp16 tiles ---------------------
__global__ __launch_bounds__(256) void qm_pre_kernel(
    const float* __restrict__ quantum, f16* __restrict__ qm_pre)
{
    __shared__ float qs[32][64];
    const int tid = threadIdx.x;
    const int qt = blockIdx.x, kt = blockIdx.y, b = blockIdx.z;
    const float* base = quantum + ((size_t)b*Lq + qt*32)*Lq + kt*64;
    #pragma unroll
    for (int i=0;i<2;++i) {
        int idx = tid + i*256;
        int r = idx >> 4, c = (idx & 15)*4;
        float4 v = *reinterpret_cast<const float4*>(base + (size_t)r*Lq + c);
        qs[r][c]=v.x; qs[r][c+1]=v.y; qs[r][c+2]=v.z; qs[r][c+3]=v.w;
    }
    __syncthreads();
    const int seg = tid >> 6, lane = tid & 63, l31 = lane & 31, hi = lane >> 5;
    f16x8 u;
    #pragma unroll
    for (int e=0;e<8;++e) {
        int key = 16*seg + 8*(e>>2) + 4*hi + (e&3);
        u[e] = (f16)qs[l31][key];
    }
    f16* outp = qm_pre + (((size_t)b*32 + kt)*64 + qt)*2048 + seg*512 + lane*8;
    *reinterpret_cast<f16x8*>(outp) = u;
}

// ---------------- flash attention: 8 waves x 32 q-rows, LDS-staged K/V -------
__global__ __launch_bounds__(512, 2) void attn8_kernel(
    const f16* __restrict__ q_h, const f16* __restrict__ k_h, const f16* __restrict__ vT_h,
    const f16* __restrict__ qm_pre, const float* __restrict__ scale,
    float* __restrict__ out)
{
    __shared__ __align__(16) char lds[32768];   // [buf][K 8KB | V 8KB] x2

    const int tid  = threadIdx.x;
    const int lane = tid & 63;
    const int wave = tid >> 6;          // 0..7
    const int l31  = lane & 31;
    const int hi   = lane >> 5;
    const int bh = blockIdx.x;
    const int qb = blockIdx.y;
    const int b_ = bh >> 4, h = bh & 15;
    const int qW = qb*256 + wave*32;    // this wave's 32 q-rows
    const int qt = qb*8 + wave;         // 32-row quantum tile index
    const float sc = scale[h];
    const float c1 = 0.125f * sc * 1.44269504f;
    const float c2 = sc * 1.44269504f;

    const f16* kbase = k_h  + (size_t)bh*Lq*HDq;
    const f16* vbase = vT_h + (size_t)bh*HDq*Lq;

    // Q fragments (B-operand: qrow=l31, d = ds*16+hi*8+e)
    f16x8 qf[4];
    {
        const f16* qb_ = q_h + ((size_t)bh*Lq + qW + l31)*HDq + hi*8;
        #pragma unroll
        for (int ds=0; ds<4; ++ds)
            qf[ds] = *reinterpret_cast<const f16x8*>(qb_ + ds*16);
    }

    f32x16 o0, o1;
    #pragma unroll
    for (int r=0;r<16;++r) { o0[r]=0.f; o1[r]=0.f; }
    float m_run = -1e30f, s_run = 0.f;

    auto STAGE = [&](int t, int buf) {
        const int k0 = t*64;
        char* LK = lds + buf*16384;
        char* LV = LK + 8192;
        int row = tid >> 3, slot = tid & 7;      // 512 thr -> 64 rows x 8 slots
        int ss = slot ^ (row & 7);
        gload_lds16(kbase + (size_t)(k0+row)*HDq + ss*8, LK + tid*16);
        gload_lds16(vbase + (size_t)row*Lq + k0 + ss*8,  LV + tid*16);
    };

    auto COMPUTE = [&](int t, int buf) {
        const char* LK = lds + buf*16384;
        const char* LV = LK + 8192;
        // quantum fragments (coalesced, element order == register order)
        f16x8 qm[4];
        const f16* qmb = qm_pre + (((size_t)b_*32 + t)*64 + qt)*2048 + lane*8;
        #pragma unroll
        for (int s=0;s<4;++s)
            qm[s] = *reinterpret_cast<const f16x8*>(qmb + s*512);

        // S^T = K Q^T (two 32-key tiles)
        f32x16 st[2];
        __builtin_amdgcn_s_setprio(1);
        #pragma unroll
        for (int kt=0;kt<2;++kt) {
            #pragma unroll
            for (int r=0;r<16;++r) st[kt][r]=0.f;
            #pragma unroll
            for (int ds=0;ds<4;++ds) {
                f16x8 ka = *reinterpret_cast<const f16x8*>(
                    LK + ((kt*32+l31)<<7) + (((ds*2+hi)^(l31&7))<<4));
                st[kt] = __builtin_amdgcn_mfma_f32_32x32x16_f16(ka, qf[ds], st[kt], 0,0,0);
            }
        }
        __builtin_amdgcn_s_setprio(0);

        // logits (base-2)
        float lg[32];
        #pragma unroll
        for (int s=0;s<4;++s)
            #pragma unroll
            for (int e=0;e<8;++e) {
                int i = s*8 + e;
                float sv = (i < 16) ? st[0][i] : st[1][i-16];
                lg[i] = sv*c1 + (float)qm[s][e]*c2;
            }

        // tile max: pairwise tree (dep depth 5)
        float tm[16];
        #pragma unroll
        for (int r=0;r<16;++r) tm[r] = fmaxf(lg[r], lg[r+16]);
        #pragma unroll
        for (int w=8; w>0; w>>=1)
            #pragma unroll
            for (int r=0;r<w;++r) tm[r] = fmaxf(tm[r], tm[r+w]);
        float tmax = fmaxf(tm[0], __shfl_xor(tm[0], 32));

        if (!__all(tmax <= m_run + 8.f)) {
            float m_new = fmaxf(m_run, tmax);
            float corr = __builtin_amdgcn_exp2f(m_run - m_new);
            m_run = m_new;
            s_run *= corr;
            #pragma unroll
            for (int r=0;r<16;++r) { o0[r] *= corr; o1[r] *= corr; }
        }

        // P = 2^(lg - m); sum via tree
        float p[32];
        #pragma unroll
        for (int r=0;r<32;++r) p[r] = __builtin_amdgcn_exp2f(lg[r] - m_run);
        float sm[16];
        #pragma unroll
        for (int r=0;r<16;++r) sm[r] = p[r] + p[r+16];
        #pragma unroll
        for (int w=8; w>0; w>>=1)
            #pragma unroll
            for (int r=0;r<w;++r) sm[r] += sm[r+w];
        s_run += sm[0];

        // pack P -> B-operand fragments
        f16x8 pb[4];
        #pragma unroll
        for (int ks=0; ks<4; ++ks) {
            int w0 = pk2(p[8*ks+0], p[8*ks+1]);
            int w1 = pk2(p[8*ks+2], p[8*ks+3]);
            int w2 = pk2(p[8*ks+4], p[8*ks+5]);
            int w3 = pk2(p[8*ks+6], p[8*ks+7]);
            swap32(w0, w2);
            swap32(w1, w3);
            union { int w[4]; f16x8 v; } u;
            u.w[0]=w0; u.w[1]=w1; u.w[2]=w2; u.w[3]=w3;
            pb[ks] = u.v;
        }

        // O^T += V^T P^T
        __builtin_amdgcn_s_setprio(1);
        #pragma unroll
        for (int ks=0; ks<4; ++ks) {
            f16x8 va0 = *reinterpret_cast<const f16x8*>(
                LV + (l31<<7)        + (((ks*2+hi)^(l31&7))<<4));
            f16x8 va1 = *reinterpret_cast<const f16x8*>(
                LV + ((32+l31)<<7)   + (((ks*2+hi)^(l31&7))<<4));
            o0 = __builtin_amdgcn_mfma_f32_32x32x16_f16(va0, pb[ks], o0, 0,0,0);
            o1 = __builtin_amdgcn_mfma_f32_32x32x16_f16(va1, pb[ks], o1, 0,0,0);
        }
        __builtin_amdgcn_s_setprio(0);
    };

    STAGE(0, 0);
    STAGE(1, 1);
    for (int t = 0; t < 31; ++t) {
        asm volatile("s_waitcnt vmcnt(2)" ::: "memory");
        __builtin_amdgcn_s_barrier();
        COMPUTE(t, t & 1);
        asm volatile("s_waitcnt lgkmcnt(0)" ::: "memory");
        __builtin_amdgcn_sched_barrier(0);
        __builtin_amdgcn_s_barrier();
        if (t < 30) STAGE(t+2, t & 1);
    }
    asm volatile("s_waitcnt vmcnt(0)" ::: "memory");
    __builtin_amdgcn_s_barrier();
    COMPUTE(31, 1);

    // epilogue
    float s_tot = s_run + __shfl_xor(s_run, 32);
    float inv = 1.0f / s_tot;
    float* ob = out + ((size_t)b_*Lq + qW + l31)*Dq + h*HDq;
    #pragma unroll
    for (int r=0;r<16;++r) {
        int drow = (r&3) + 8*(r>>2) + 4*hi;
        ob[drow]      = o0[r]*inv;
        ob[32 + drow] = o1[r]*inv;
    }
}

extern "C" void kernel_launch(void* const* d_in, const int* in_sizes, int n_in,
                              void* d_out, int out_size, void* d_ws, size_t ws_size,
                              hipStream_t stream) {
    const float* x       = (const float*)d_in[0];
    const float* quantum = (const float*)d_in[1];
    const float* wq      = (const float*)d_in[2];
    const float* wk      = (const float*)d_in[3];
    const float* wv      = (const float*)d_in[4];
    const float* scale   = (const float*)d_in[5];
    float* out = (float*)d_out;

    f16* ws     = (f16*)d_ws;
    f16* x_h    = ws;
    f16* wq_h   = ws + 4194304;
    f16* wk_h   = ws + 5242880;
    f16* wv_h   = ws + 6291456;
    f16* q_h    = ws + 7340032;
    f16* k_h    = ws + 11534336;
    f16* vT_h   = ws + 15728640;
    f16* qm_pre = ws + 19922944;

    convert_kernel<<<1024, 256, 0, stream>>>(x, wq, wk, wv, x_h, wq_h, wk_h, wv_h);

    dim3 gq(64, 32, 2);
    qm_pre_kernel<<<gq, 256, 0, stream>>>(quantum, qm_pre);

    dim3 g1(Dq/GBN, (Bq*Lq)/GBM, 3);
    qkv_mfma_kernel<<<g1, 256, 0, stream>>>(x_h, wq_h, wk_h, wv_h, q_h, k_h, vT_h);

    // all 8 q-blocks of one bh land on one XCD (linear id % 8 = bh % 8)
    dim3 g2(Bq*Hq, Lq/256);
    attn8_kernel<<<g2, 512, 0, stream>>>(q_h, k_h, vT_h, qm_pre, scale, out);
}

// Round 7
// 130.732 us; speedup vs baseline: 1.7150x; 1.0534x over previous
//
#include <hip/hip_runtime.h>

#define Bq 2
#define Lq 2048
#define Dq 1024
#define Hq 16
#define HDq 64

typedef _Float16 f16;
typedef _Float16 f16x8 __attribute__((ext_vector_type(8)));
typedef _Float16 f16x4 __attribute__((ext_vector_type(4)));
typedef __fp16 hf16x2 __attribute__((ext_vector_type(2)));
typedef float f32x4 __attribute__((ext_vector_type(4)));
typedef float f32x16 __attribute__((ext_vector_type(16)));

__device__ __forceinline__ void gload_lds16(const void* g, void* l) {
    __builtin_amdgcn_global_load_lds(
        (const __attribute__((address_space(1))) unsigned int*)g,
        (__attribute__((address_space(3))) unsigned int*)l, 16, 0, 0);
}

__device__ __forceinline__ void swap32(int& a, int& b) {
    asm volatile("v_permlane32_swap_b32 %0, %1" : "+v"(a), "+v"(b));
}

__device__ __forceinline__ int pk2(float a, float b) {
    hf16x2 v = __builtin_amdgcn_cvt_pkrtz(a, b);
    return __builtin_bit_cast(int, v);
}

// ---------------- fp32 -> fp16 conversion ------------------------------------
__global__ __launch_bounds__(256) void convert_kernel(
    const float* __restrict__ x,
    const float* __restrict__ wq, const float* __restrict__ wk, const float* __restrict__ wv,
    f16* __restrict__ x_h, f16* __restrict__ wq_h, f16* __restrict__ wk_h, f16* __restrict__ wv_h)
{
    const int NX = Bq*Lq*Dq;
    const int NW = Dq*Dq;
    const int total4 = (NX + 3*NW) / 4;
    for (int i = blockIdx.x*blockDim.x + threadIdx.x; i < total4;
         i += gridDim.x*blockDim.x) {
        int e = i * 4;
        const float* src; f16* dst; int off;
        if (e < NX) { src = x; dst = x_h; off = e; }
        else {
            int t = e - NX; int w = t >> 20; off = t & (NW-1);
            src = (w==0) ? wq : (w==1) ? wk : wv;
            dst = (w==0) ? wq_h : (w==1) ? wk_h : wv_h;
        }
        float4 v = *reinterpret_cast<const float4*>(src + off);
        f16x4 hv; hv.x=(f16)v.x; hv.y=(f16)v.y; hv.z=(f16)v.z; hv.w=(f16)v.w;
        *reinterpret_cast<f16x4*>(dst + off) = hv;
    }
}

// ---------------- QKV projection, fp16 MFMA ----------------------------------
#define GBM 128
#define GBN 128
#define GBK 32

__global__ __launch_bounds__(256) void qkv_mfma_kernel(
    const f16* __restrict__ x_h,
    const f16* __restrict__ wq_h, const f16* __restrict__ wk_h, const f16* __restrict__ wv_h,
    f16* __restrict__ q_h, f16* __restrict__ k_h, f16* __restrict__ vT_h)
{
    __shared__ __align__(16) f16 As[GBM*GBK];
    __shared__ __align__(16) f16 Bs[GBN*GBK];

    const int tid  = threadIdx.x;
    const int lane = tid & 63;
    const int wave = tid >> 6;
    const int wr = wave >> 1, wc = wave & 1;
    const int l15 = lane & 15, l4 = lane >> 4;
    const int n0 = blockIdx.x * GBN;
    const int m0 = blockIdx.y * GBM;
    const int z  = blockIdx.z;
    const f16* W = (z==0) ? wq_h : (z==1) ? wk_h : wv_h;

    const int sslot = tid & 3;

    f32x4 acc[4][4];
    #pragma unroll
    for (int i=0;i<4;++i)
        #pragma unroll
        for (int j=0;j<4;++j) acc[i][j] = f32x4{0.f,0.f,0.f,0.f};

    for (int kt = 0; kt < Dq; kt += GBK) {
        __syncthreads();
        #pragma unroll
        for (int j = 0; j < 2; ++j) {
            int slotIdx = tid + j*256;
            int row = slotIdx >> 2;
            gload_lds16(x_h + (size_t)(m0+row)*Dq + kt + sslot*8,
                        (char*)As + slotIdx*16);
            gload_lds16(W   + (size_t)(n0+row)*Dq + kt + sslot*8,
                        (char*)Bs + slotIdx*16);
        }
        __syncthreads();

        f16x8 a[4], b[4];
        #pragma unroll
        for (int m=0;m<4;++m) {
            int row = wr*64 + m*16 + l15;
            a[m] = *reinterpret_cast<const f16x8*>((const char*)As + row*64 + l4*16);
        }
        #pragma unroll
        for (int n=0;n<4;++n) {
            int row = wc*64 + n*16 + l15;
            b[n] = *reinterpret_cast<const f16x8*>((const char*)Bs + row*64 + l4*16);
        }
        #pragma unroll
        for (int m=0;m<4;++m)
            #pragma unroll
            for (int n=0;n<4;++n)
                acc[m][n] = __builtin_amdgcn_mfma_f32_16x16x32_f16(a[m], b[n], acc[m][n], 0,0,0);
    }

    #pragma unroll
    for (int m=0;m<4;++m) {
        #pragma unroll
        for (int r=0;r<4;++r) {
            int grow = m0 + wr*64 + m*16 + l4*4 + r;
            int b_   = grow >> 11;
            int lrow = grow & (Lq-1);
            #pragma unroll
            for (int n=0;n<4;++n) {
                int gcol = n0 + wc*64 + n*16 + l15;
                int h = gcol >> 6, d = gcol & 63;
                int bh = b_*Hq + h;
                f16 val = (f16)acc[m][n][r];
                if (z==0)      q_h[((size_t)bh*Lq + lrow)*HDq + d] = val;
                else if (z==1) k_h[((size_t)bh*Lq + lrow)*HDq + d] = val;
                else           vT_h[((size_t)bh*HDq + d)*Lq + lrow] = val;
            }
        }
    }
}

// ---------------- quantum -> fragment-ordered fp16 tiles ---------------------
__global__ __launch_bounds__(256) void qm_pre_kernel(
    const float* __restrict__ quantum, f16* __restrict__ qm_pre)
{
    __shared__ float qs[32][64];
    const int tid = threadIdx.x;
    const int qt = blockIdx.x, kt = blockIdx.y, b = blockIdx.z;
    const float* base = quantum + ((size_t)b*Lq + qt*32)*Lq + kt*64;
    #pragma unroll
    for (int i=0;i<2;++i) {
        int idx = tid + i*256;
        int r = idx >> 4, c = (idx & 15)*4;
        float4 v = *reinterpret_cast<const float4*>(base + (size_t)r*Lq + c);
        qs[r][c]=v.x; qs[r][c+1]=v.y; qs[r][c+2]=v.z; qs[r][c+3]=v.w;
    }
    __syncthreads();
    const int seg = tid >> 6, lane = tid & 63, l31 = lane & 31, hi = lane >> 5;
    f16x8 u;
    #pragma unroll
    for (int e=0;e<8;++e) {
        int key = 16*seg + 8*(e>>2) + 4*hi + (e&3);
        u[e] = (f16)qs[l31][key];
    }
    f16* outp = qm_pre + (((size_t)b*32 + kt)*64 + qt)*2048 + seg*512 + lane*8;
    *reinterpret_cast<f16x8*>(outp) = u;
}

// ---------------- flash attention: 4 waves x 32 q-rows, triple-buffered ------
// single barrier per iter, counted vmcnt, qm register prefetch (ping-pong)
__global__ __launch_bounds__(256, 2) void attn4_kernel(
    const f16* __restrict__ q_h, const f16* __restrict__ k_h, const f16* __restrict__ vT_h,
    const f16* __restrict__ qm_pre, const float* __restrict__ scale,
    float* __restrict__ out)
{
    __shared__ __align__(16) char lds[49152];   // 3 bufs x [K 8KB | V 8KB]

    const int tid  = threadIdx.x;
    const int lane = tid & 63;
    const int wave = tid >> 6;          // 0..3
    const int l31  = lane & 31;
    const int hi   = lane >> 5;
    const int bh = blockIdx.x;
    const int qb = blockIdx.y;
    const int b_ = bh >> 4, h = bh & 15;
    const int qW = qb*128 + wave*32;    // this wave's 32 q-rows
    const int qt = qb*4 + wave;         // 32-row quantum tile index
    const float sc = scale[h];
    const float c1 = 0.125f * sc * 1.44269504f;
    const float c2 = sc * 1.44269504f;

    const f16* kbase = k_h  + (size_t)bh*Lq*HDq;
    const f16* vbase = vT_h + (size_t)bh*HDq*Lq;

    // Q fragments (B-operand: qrow=l31, d = ds*16+hi*8+e)
    f16x8 qf[4];
    {
        const f16* qb_ = q_h + ((size_t)bh*Lq + qW + l31)*HDq + hi*8;
        #pragma unroll
        for (int ds=0; ds<4; ++ds)
            qf[ds] = *reinterpret_cast<const f16x8*>(qb_ + ds*16);
    }

    f32x16 o0, o1;
    #pragma unroll
    for (int r=0;r<16;++r) { o0[r]=0.f; o1[r]=0.f; }
    float m_run = -1e30f, s_run = 0.f;

    auto STAGE = [&](int t, int buf) {
        const int k0 = t*64;
        char* LK = lds + buf*16384;
        char* LV = LK + 8192;
        #pragma unroll
        for (int i=0;i<2;++i) {
            int g = tid + i*256;                 // 0..511
            int row = g >> 3, slot = g & 7;
            int ss = slot ^ (row & 7);
            gload_lds16(kbase + (size_t)(k0+row)*HDq + ss*8, LK + g*16);
            gload_lds16(vbase + (size_t)row*Lq + k0 + ss*8,  LV + g*16);
        }
    };

    auto QMLOAD = [&](int t, f16x8 (&qm)[4]) {
        const f16* qmb = qm_pre + (((size_t)b_*32 + t)*64 + qt)*2048 + lane*8;
        #pragma unroll
        for (int s=0;s<4;++s)
            qm[s] = *reinterpret_cast<const f16x8*>(qmb + s*512);
    };

    auto COMPUTE = [&](int t, int buf, f16x8 (&qmc)[4], f16x8 (&qmn)[4]) {
        const char* LK = lds + buf*16384;
        const char* LV = LK + 8192;
        // prefetch next iteration's quantum fragments (consumed next iter)
        int tn = (t+1 < 32) ? t+1 : 31;
        QMLOAD(tn, qmn);

        // S^T = K Q^T (two 32-key tiles)
        f32x16 st[2];
        __builtin_amdgcn_s_setprio(1);
        #pragma unroll
        for (int kt=0;kt<2;++kt) {
            #pragma unroll
            for (int r=0;r<16;++r) st[kt][r]=0.f;
            #pragma unroll
            for (int ds=0;ds<4;++ds) {
                f16x8 ka = *reinterpret_cast<const f16x8*>(
                    LK + ((kt*32+l31)<<7) + (((ds*2+hi)^(l31&7))<<4));
                st[kt] = __builtin_amdgcn_mfma_f32_32x32x16_f16(ka, qf[ds], st[kt], 0,0,0);
            }
        }
        __builtin_amdgcn_s_setprio(0);

        // logits (base-2)
        float lg[32];
        #pragma unroll
        for (int s=0;s<4;++s)
            #pragma unroll
            for (int e=0;e<8;++e) {
                int i = s*8 + e;
                float sv = (i < 16) ? st[0][i] : st[1][i-16];
                lg[i] = sv*c1 + (float)qmc[s][e]*c2;
            }

        // tile max: pairwise tree
        float tm[16];
        #pragma unroll
        for (int r=0;r<16;++r) tm[r] = fmaxf(lg[r], lg[r+16]);
        #pragma unroll
        for (int w=8; w>0; w>>=1)
            #pragma unroll
            for (int r=0;r<w;++r) tm[r] = fmaxf(tm[r], tm[r+w]);
        float tmax = fmaxf(tm[0], __shfl_xor(tm[0], 32));

        if (!__all(tmax <= m_run + 8.f)) {
            float m_new = fmaxf(m_run, tmax);
            float corr = __builtin_amdgcn_exp2f(m_run - m_new);
            m_run = m_new;
            s_run *= corr;
            #pragma unroll
            for (int r=0;r<16;++r) { o0[r] *= corr; o1[r] *= corr; }
        }

        // P = 2^(lg - m); sum via tree
        float p[32];
        #pragma unroll
        for (int r=0;r<32;++r) p[r] = __builtin_amdgcn_exp2f(lg[r] - m_run);
        float sm[16];
        #pragma unroll
        for (int r=0;r<16;++r) sm[r] = p[r] + p[r+16];
        #pragma unroll
        for (int w=8; w>0; w>>=1)
            #pragma unroll
            for (int r=0;r<w;++r) sm[r] += sm[r+w];
        s_run += sm[0];

        // pack P -> B-operand fragments
        f16x8 pb[4];
        #pragma unroll
        for (int ks=0; ks<4; ++ks) {
            int w0 = pk2(p[8*ks+0], p[8*ks+1]);
            int w1 = pk2(p[8*ks+2], p[8*ks+3]);
            int w2 = pk2(p[8*ks+4], p[8*ks+5]);
            int w3 = pk2(p[8*ks+6], p[8*ks+7]);
            swap32(w0, w2);
            swap32(w1, w3);
            union { int w[4]; f16x8 v; } u;
            u.w[0]=w0; u.w[1]=w1; u.w[2]=w2; u.w[3]=w3;
            pb[ks] = u.v;
        }

        // O^T += V^T P^T
        __builtin_amdgcn_s_setprio(1);
        #pragma unroll
        for (int ks=0; ks<4; ++ks) {
            f16x8 va0 = *reinterpret_cast<const f16x8*>(
                LV + (l31<<7)        + (((ks*2+hi)^(l31&7))<<4));
            f16x8 va1 = *reinterpret_cast<const f16x8*>(
                LV + ((32+l31)<<7)   + (((ks*2+hi)^(l31&7))<<4));
            o0 = __builtin_amdgcn_mfma_f32_32x32x16_f16(va0, pb[ks], o0, 0,0,0);
            o1 = __builtin_amdgcn_mfma_f32_32x32x16_f16(va1, pb[ks], o1, 0,0,0);
        }
        __builtin_amdgcn_s_setprio(0);
    };

    f16x8 qmE[4], qmO[4];

    // prologue: qm for t=0, then K/V tiles 0,1
    QMLOAD(0, qmE);
    STAGE(0, 0);
    STAGE(1, 1);

    #define VMW(n) asm volatile("s_waitcnt vmcnt(" #n ")" ::: "memory")

    // t = 0  (younger than STAGE(0): STAGE(1)=4)
    VMW(4);  __builtin_amdgcn_s_barrier();
    STAGE(2, 2);  COMPUTE(0, 0, qmE, qmO);
    // t = 1  (younger than STAGE(1): STAGE(2)+Qp(0)=8)
    VMW(8);  __builtin_amdgcn_s_barrier();
    STAGE(3, 0);  COMPUTE(1, 1, qmO, qmE);
    // t = 2..29 (steady: younger than STAGE(t): Qp+STAGE+Qp = 12)
    for (int t = 2; t < 30; t += 2) {
        VMW(12); __builtin_amdgcn_s_barrier();
        STAGE(t+2, (t+2)%3); COMPUTE(t, t%3, qmE, qmO);
        VMW(12); __builtin_amdgcn_s_barrier();
        STAGE(t+3, (t+3)%3); COMPUTE(t+1, (t+1)%3, qmO, qmE);
    }
    // t = 30 (younger than STAGE(30): Qp(28)+STAGE(31)+Qp(29)=12)
    VMW(12); __builtin_amdgcn_s_barrier();
    COMPUTE(30, 0, qmE, qmO);
    // t = 31 (younger than STAGE(31): Qp(29)+Qp(30)=8)
    VMW(8);  __builtin_amdgcn_s_barrier();
    COMPUTE(31, 1, qmO, qmE);

    #undef VMW

    // epilogue
    float s_tot = s_run + __shfl_xor(s_run, 32);
    float inv = 1.0f / s_tot;
    float* ob = out + ((size_t)b_*Lq + qW + l31)*Dq + h*HDq;
    #pragma unroll
    for (int r=0;r<16;++r) {
        int drow = (r&3) + 8*(r>>2) + 4*hi;
        ob[drow]      = o0[r]*inv;
        ob[32 + drow] = o1[r]*inv;
    }
}

extern "C" void kernel_launch(void* const* d_in, const int* in_sizes, int n_in,
                              void* d_out, int out_size, void* d_ws, size_t ws_size,
                              hipStream_t stream) {
    const float* x       = (const float*)d_in[0];
    const float* quantum = (const float*)d_in[1];
    const float* wq      = (const float*)d_in[2];
    const float* wk      = (const float*)d_in[3];
    const float* wv      = (const float*)d_in[4];
    const float* scale   = (const float*)d_in[5];
    float* out = (float*)d_out;

    f16* ws     = (f16*)d_ws;
    f16* x_h    = ws;
    f16* wq_h   = ws + 4194304;
    f16* wk_h   = ws + 5242880;
    f16* wv_h   = ws + 6291456;
    f16* q_h    = ws + 7340032;
    f16* k_h    = ws + 11534336;
    f16* vT_h   = ws + 15728640;
    f16* qm_pre = ws + 19922944;

    convert_kernel<<<1024, 256, 0, stream>>>(x, wq, wk, wv, x_h, wq_h, wk_h, wv_h);

    dim3 gq(64, 32, 2);
    qm_pre_kernel<<<gq, 256, 0, stream>>>(quantum, qm_pre);

    dim3 g1(Dq/GBN, (Bq*Lq)/GBM, 3);
    qkv_mfma_kernel<<<g1, 256, 0, stream>>>(x_h, wq_h, wk_h, wv_h, q_h, k_h, vT_h);

    // all q-blocks of one bh land on one XCD (linear id % 8 = bh % 8)
    dim3 g2(Bq*Hq, Lq/128);
    attn4_kernel<<<g2, 256, 0, stream>>>(q_h, k_h, vT_h, qm_pre, scale, out);
}